// Round 7
// baseline (252.183 us; speedup 1.0000x reference)
//
#include <hip/hip_runtime.h>
#include <math.h>

#define DIM 1024

typedef float f32x4 __attribute__((ext_vector_type(4)));

// ---------------------------------------------------------------------------
// TWO-PASS STREAMING SPLIT (round 7).
//
// Measured history: fused single-pass kernels run at ~3.2 TB/s effective
// (82.6 us r3, 86.7 us r4, <78.7 us r6) while the harness's pure-write fill
// sustains 6.8 TB/s. RPW=4 (r4) proved latency chains are NOT the limit.
// Remaining theory: the coupled read+reduce->write structure never gives
// DRAM a clean stream. Split into two passes that each look like the fill:
//   pass1: pure read stream  (134 MB HBM)  -> s[row]      (128 KB)
//   pass2: L3 read (x is MALL-resident from pass1) -> NT write stream
//
// Weight algebra (row-independent, rebuilt in-register; VALU is ~87% idle):
//   level l applies z <- (a_l - i b_l) z, block j = p >> (l-1), l=1..9.
//   pass1 needs only |w_p|^2 = prod_l (a_l^2 + b_l^2)  (real chain);
//   pass2 needs the full complex w_p.
// Map algebra (exact): u = s1*x, s1 = artanh(r)/r, r = ||x||;
//   ||y||^2 = s1^2 * sum_p |w_p|^2 |x_pair|^2;
//   out = s1 * tanh(vn)/vn * (w (*) x), vn = max(s1*sqrt(sum2), 1e-8).
// ---------------------------------------------------------------------------

// float2 offsets of level-l param blocks (l = 2..9), j = q >> (l-2):
#define F_TABLE {1536, 1792, 1920, 1984, 2016, 2032, 2040, 2044}

// ---------------- Pass 1: per-row combined scale s = s1 * tanh(vn)/vn ------
__global__ __launch_bounds__(256) void hb_reduce_kernel(
        const float* __restrict__ x,
        const float* __restrict__ params,
        float* __restrict__ srow, int sstride,
        int rows) {
    const int lane = threadIdx.x & 63;
    const int wave = threadIdx.x >> 6;
    const int row = blockIdx.x * 4 + wave;
    if (row >= rows) return;

    const float4* xrow = (const float4*)(x + (size_t)row * DIM);
    float4 xv[4];
#pragma unroll
    for (int i = 0; i < 4; ++i) xv[i] = xrow[lane + 64 * i];

    const float2* pf2 = (const float2*)params;
    float p1 = 0.0f, p2 = 0.0f;
#pragma unroll
    for (int i = 0; i < 4; ++i) {
        const int q = lane + 64 * i;
        const int F[8] = F_TABLE;
        float c2 = 1.0f;                       // prod_{l=2..9} |f_l|^2
#pragma unroll
        for (int l = 0; l < 8; ++l) {
            float2 ab = pf2[F[l] + (q >> l)];
            c2 *= ab.x * ab.x + ab.y * ab.y;
        }
        float2 ab0 = pf2[1024 + 2 * q];        // level 1, pair 2q
        float2 ab1 = pf2[1024 + 2 * q + 1];    // level 1, pair 2q+1
        float m0 = c2 * (ab0.x * ab0.x + ab0.y * ab0.y);
        float m1 = c2 * (ab1.x * ab1.x + ab1.y * ab1.y);
        float a0 = xv[i].x * xv[i].x + xv[i].y * xv[i].y;
        float a1 = xv[i].z * xv[i].z + xv[i].w * xv[i].w;
        p1 += a0 + a1;
        p2 += m0 * a0 + m1 * a1;
    }

#pragma unroll
    for (int o = 32; o > 0; o >>= 1) {
        p1 += __shfl_xor(p1, o);
        p2 += __shfl_xor(p2, o);
    }

    if (lane == 0) {
        float r = sqrtf(p1);
        float s1 = (r > 1e-12f)
                       ? (0.5f * logf((1.0f + r) / (1.0f - r)) / r)
                       : 1.0f;                           // artanh(r)/r
        float vn = fmaxf(s1 * sqrtf(p2), 1e-8f);         // ||y||
        srow[(size_t)row * sstride] = s1 * (tanhf(vn) / vn);
    }
}

// ---------------- Pass 2: out = s * (w (*) x), NT stores -------------------
__global__ __launch_bounds__(256) void hb_scale_kernel(
        const float* __restrict__ x,
        const float* __restrict__ params,
        const float* __restrict__ srow, int sstride,
        float* __restrict__ out,
        int rows) {
    const int lane = threadIdx.x & 63;
    const int wave = threadIdx.x >> 6;
    const int row = blockIdx.x * 4 + wave;
    if (row >= rows) return;

    // x reads: expected L3(MALL)-resident from pass 1
    const float4* xrow = (const float4*)(x + (size_t)row * DIM);
    float4 xv[4];
#pragma unroll
    for (int i = 0; i < 4; ++i) xv[i] = xrow[lane + 64 * i];

    float s = srow[(size_t)row * sstride];     // uniform addr -> 1 request

    // full complex weights for this thread's 8 pairs
    const float2* pf2 = (const float2*)params;
    float4 wv[4];
#pragma unroll
    for (int i = 0; i < 4; ++i) {
        const int q = lane + 64 * i;
        const int F[8] = F_TABLE;
        float cr = 1.0f, ci = 0.0f;
#pragma unroll
        for (int l = 0; l < 8; ++l) {          // levels 2..9
            float2 ab = pf2[F[l] + (q >> l)];
            float nr = cr * ab.x + ci * ab.y;  // (cr + i ci)(a - i b)
            float ni = ci * ab.x - cr * ab.y;
            cr = nr;
            ci = ni;
        }
        float2 ab0 = pf2[1024 + 2 * q];
        float2 ab1 = pf2[1024 + 2 * q + 1];
        wv[i].x = cr * ab0.x + ci * ab0.y;
        wv[i].y = ci * ab0.x - cr * ab0.y;
        wv[i].z = cr * ab1.x + ci * ab1.y;
        wv[i].w = ci * ab1.x - cr * ab1.y;
    }

    f32x4* orow = (f32x4*)(out + (size_t)row * DIM);
#pragma unroll
    for (int i = 0; i < 4; ++i) {
        f32x4 o4;
        o4.x = s * (wv[i].x * xv[i].x - wv[i].y * xv[i].y);
        o4.y = s * (wv[i].x * xv[i].y + wv[i].y * xv[i].x);
        o4.z = s * (wv[i].z * xv[i].z - wv[i].w * xv[i].w);
        o4.w = s * (wv[i].z * xv[i].w + wv[i].w * xv[i].z);
        __builtin_nontemporal_store(o4, &orow[lane + 64 * i]);
    }
}

extern "C" void kernel_launch(void* const* d_in, const int* in_sizes, int n_in,
                              void* d_out, int out_size, void* d_ws, size_t ws_size,
                              hipStream_t stream) {
    const float* x = (const float*)d_in[0];
    const float* params = (const float*)d_in[1];
    float* out = (float*)d_out;

    // in_sizes[] is in ELEMENTS (verified round 3: /DIM passes).
    int rows = in_sizes[0] / DIM;

    // s[row] scratch: prefer workspace; else alias out[row*DIM] (pass 2
    // reads it before overwriting that row within the same wave -> safe).
    float* srow;
    int sstride;
    if (ws_size >= (size_t)rows * sizeof(float)) {
        srow = (float*)d_ws;
        sstride = 1;
    } else {
        srow = out;
        sstride = DIM;
    }

    int blocks = (rows + 3) / 4;   // 4 waves/block, 1 row per wave
    hb_reduce_kernel<<<blocks, 256, 0, stream>>>(x, params, srow, sstride, rows);
    hb_scale_kernel<<<blocks, 256, 0, stream>>>(x, params, srow, sstride, out, rows);
}

// Round 13
// 235.250 us; speedup vs baseline: 1.0720x; 1.0720x over previous
//
#include <hip/hip_runtime.h>
#include <math.h>

#define DIM 1024

typedef float f32x4 __attribute__((ext_vector_type(4)));

// ---------------------------------------------------------------------------
// PERSISTENT-WAVE, SOFTWARE-PIPELINED (round 8; resubmitted r9-r13 —
// infra failures, never measured).
//
// Evidence: harness fill sustains 6.8 TB/s at 9.4% occupancy with long-lived
// grid-stride waves; our short-lived wave-per-row kernels get ~5.3 B/cy/CU
// (half of copy's ~10) because each wave issues 4 loads, fully drains through
// a reduce, stores, and dies. r4 (RPW=4, same phase structure) was null;
// r7 (two-pass) regressed +18us. This version makes waves persistent:
// 1024 blocks = 4096 waves, 8 rows each, A/B double-buffered in registers.
// Row n+1's loads are issued BEFORE row n's reduce -> the compiler's counted
// vmcnt lets compute wait only on its own row; loads and NT stores stream
// continuously like the fill.
//
// Weight algebra (computed ONCE per wave, amortized over its 8 rows):
//   level l applies z <- (a_l - i b_l) z, block j = p >> (l-1), l=1..9
//   (l=0 is a no-op). Pairs 2q,2q+1 share levels 2..9: c = prod f_l(q>>(l-2)),
//   w(2q)=c*f1(2q), w(2q+1)=c*f1(2q+1).
// Map algebra (exact): u = s1*x, s1 = artanh(r)/r, r = ||x||;
//   ||y||^2 = s1^2 * sum_p |w_p|^2 |x_pair|^2;
//   out = s1 * tanh(vn)/vn * (w (*) x), vn = max(s1*sqrt(sum2), 1e-8).
// ---------------------------------------------------------------------------

__device__ __forceinline__ void hb_load_row(const float* __restrict__ x,
                                            int row, int lane, float4 v[4]) {
    const float4* xrow = (const float4*)(x + (size_t)row * DIM);
#pragma unroll
    for (int i = 0; i < 4; ++i) v[i] = xrow[lane + 64 * i];
}

__device__ __forceinline__ void hb_process_store(
        const float4 xv[4], const float4 wv[4],
        const float m0[4], const float m1[4],
        float* __restrict__ out, int row, int lane) {
    float p1 = 0.0f, p2 = 0.0f;
#pragma unroll
    for (int i = 0; i < 4; ++i) {
        float a0 = xv[i].x * xv[i].x + xv[i].y * xv[i].y;
        float a1 = xv[i].z * xv[i].z + xv[i].w * xv[i].w;
        p1 += a0 + a1;
        p2 += m0[i] * a0 + m1[i] * a1;
    }
#pragma unroll
    for (int o = 32; o > 0; o >>= 1) {
        p1 += __shfl_xor(p1, o);
        p2 += __shfl_xor(p2, o);
    }
    float r = sqrtf(p1);
    float s1 = (r > 1e-12f) ? (0.5f * logf((1.0f + r) / (1.0f - r)) / r)
                            : 1.0f;                      // artanh(r)/r
    float vn = fmaxf(s1 * sqrtf(p2), 1e-8f);             // ||y||
    float s = s1 * (tanhf(vn) / vn);

    f32x4* orow = (f32x4*)(out + (size_t)row * DIM);
#pragma unroll
    for (int i = 0; i < 4; ++i) {
        f32x4 o4;
        o4.x = s * (wv[i].x * xv[i].x - wv[i].y * xv[i].y);
        o4.y = s * (wv[i].x * xv[i].y + wv[i].y * xv[i].x);
        o4.z = s * (wv[i].z * xv[i].z - wv[i].w * xv[i].w);
        o4.w = s * (wv[i].z * xv[i].w + wv[i].w * xv[i].z);
        __builtin_nontemporal_store(o4, &orow[lane + 64 * i]);
    }
}

__global__ __launch_bounds__(256) void hb_persistent_kernel(
        const float* __restrict__ x,
        const float* __restrict__ params,
        float* __restrict__ out,
        int rows) {
    const int lane = threadIdx.x & 63;
    const int gwave = blockIdx.x * 4 + (threadIdx.x >> 6);
    const int nwaves = gridDim.x * 4;

    int rowA = gwave;
    if (rowA >= rows) return;

    // issue first row's loads immediately; weight compute overlaps the wait
    float4 A[4], B[4];
    hb_load_row(x, rowA, lane, A);

    // ---- butterfly weights, once per wave ----
    // float2 offsets of level-l blocks: l=1 -> 1024; l=2..9 -> F[l-2]
    const float2* pf2 = (const float2*)params;
    float4 wv[4];
    float m0[4], m1[4];
#pragma unroll
    for (int i = 0; i < 4; ++i) {
        const int q = lane + 64 * i;
        const int F[8] = {1536, 1792, 1920, 1984, 2016, 2032, 2040, 2044};
        float cr = 1.0f, ci = 0.0f;
#pragma unroll
        for (int l = 0; l < 8; ++l) {          // levels 2..9, j = q >> l
            float2 ab = pf2[F[l] + (q >> l)];
            float nr = cr * ab.x + ci * ab.y;  // (cr + i ci)(a - i b)
            float ni = ci * ab.x - cr * ab.y;
            cr = nr;
            ci = ni;
        }
        float2 ab0 = pf2[1024 + 2 * q];        // level 1, pair 2q
        float2 ab1 = pf2[1024 + 2 * q + 1];    // level 1, pair 2q+1
        wv[i].x = cr * ab0.x + ci * ab0.y;
        wv[i].y = ci * ab0.x - cr * ab0.y;
        wv[i].z = cr * ab1.x + ci * ab1.y;
        wv[i].w = ci * ab1.x - cr * ab1.y;
        m0[i] = wv[i].x * wv[i].x + wv[i].y * wv[i].y;
        m1[i] = wv[i].z * wv[i].z + wv[i].w * wv[i].w;
    }

    // ---- pipelined grid-stride loop: prefetch next row, process current ----
    for (;;) {
        int rowB = rowA + nwaves;
        if (rowB < rows) hb_load_row(x, rowB, lane, B);   // in flight past A
        hb_process_store(A, wv, m0, m1, out, rowA, lane);
        if (rowB >= rows) return;

        rowA = rowB + nwaves;
        if (rowA < rows) hb_load_row(x, rowA, lane, A);   // in flight past B
        hb_process_store(B, wv, m0, m1, out, rowB, lane);
        if (rowA >= rows) return;
    }
}

extern "C" void kernel_launch(void* const* d_in, const int* in_sizes, int n_in,
                              void* d_out, int out_size, void* d_ws, size_t ws_size,
                              hipStream_t stream) {
    const float* x = (const float*)d_in[0];
    const float* params = (const float*)d_in[1];
    float* out = (float*)d_out;

    // in_sizes[] is in ELEMENTS (verified round 3: /DIM passes).
    int rows = in_sizes[0] / DIM;

    // Persistent grid: 1024 blocks x 4 waves = 4096 waves, fully co-resident
    // (256 CU x 16 waves/CU), 8 rows per wave at rows=32768.
    int maxb = 1024;
    int need = (rows + 3) / 4;
    int blocks = need < maxb ? need : maxb;
    hb_persistent_kernel<<<blocks, 256, 0, stream>>>(x, params, out, rows);
}